// Round 1
// baseline (206.935 us; speedup 1.0000x reference)
//
#include <hip/hip_runtime.h>

#define BATCH 512
#define PIX   65536
#define NOUT  512
#define COUT  4
#define NCLS  10

#define CHUNKS 4
#define CHUNK  (PIX / CHUNKS)   // 16384 pixels per block

// ---------------------------------------------------------------------------
// Kernel 1: Weff[j,k] = sum_c W_fgl[c,j] * W_fc[(c*NOUT+j)*NCLS + k]
//           cst[k]   = sum_{c,j} b_fgl[c,j] * W_fc[(c*NOUT+j)*NCLS + k] + b_fc[k]
// cst must be zeroed before this kernel (memset on d_ws).
// ---------------------------------------------------------------------------
__global__ __launch_bounds__(256) void weff_kernel(
    const float* __restrict__ W_fgl, const float* __restrict__ b_fgl,
    const float* __restrict__ W_fc,  const float* __restrict__ b_fc,
    float* __restrict__ Weff, float* __restrict__ cst)
{
    int j = blockIdx.x * blockDim.x + threadIdx.x;
    if (j >= NOUT) return;

    float wf[COUT], bf[COUT];
#pragma unroll
    for (int c = 0; c < COUT; ++c) {
        wf[c] = W_fgl[c * NOUT + j];
        bf[c] = b_fgl[c * NOUT + j];
    }

    float cpart[NCLS];
#pragma unroll
    for (int k = 0; k < NCLS; ++k) {
        float w = 0.f, cb = 0.f;
#pragma unroll
        for (int c = 0; c < COUT; ++c) {
            float wfc = W_fc[(c * NOUT + j) * NCLS + k];
            w  += wf[c] * wfc;
            cb += bf[c] * wfc;
        }
        Weff[j * NCLS + k] = w;
        cpart[k] = cb;
    }
#pragma unroll
    for (int k = 0; k < NCLS; ++k) atomicAdd(&cst[k], cpart[k]);
    if (j < NCLS) atomicAdd(&cst[j], b_fc[j]);
}

// ---------------------------------------------------------------------------
// Kernel 2: h[n,j] = sum_{p: seg[p]==j} x[n,p]
// One block per (row, chunk). Coalesced float4 x loads; LDS histogram;
// global atomicAdd of the 512 partial bins. h must be zeroed beforehand.
// ---------------------------------------------------------------------------
__global__ __launch_bounds__(256) void segsum_kernel(
    const float* __restrict__ x, const int* __restrict__ seg,
    float* __restrict__ h)
{
    const int n     = blockIdx.x;
    const int chunk = blockIdx.y;
    const int t     = threadIdx.x;

    __shared__ float hb[NOUT];
    hb[t] = 0.f;
    hb[t + 256] = 0.f;
    __syncthreads();

    const float4* __restrict__ x4 =
        (const float4*)(x + (size_t)n * PIX + (size_t)chunk * CHUNK);
    const int4* __restrict__ s4 =
        (const int4*)(seg + (size_t)chunk * CHUNK);

#pragma unroll 4
    for (int it = 0; it < CHUNK / (256 * 4); ++it) {
        float4 xv = x4[it * 256 + t];
        int4   sv = s4[it * 256 + t];
        atomicAdd(&hb[sv.x], xv.x);
        atomicAdd(&hb[sv.y], xv.y);
        atomicAdd(&hb[sv.z], xv.z);
        atomicAdd(&hb[sv.w], xv.w);
    }
    __syncthreads();

    atomicAdd(&h[n * NOUT + t],       hb[t]);
    atomicAdd(&h[n * NOUT + t + 256], hb[t + 256]);
}

// ---------------------------------------------------------------------------
// Kernel 3: out[n,k] = sum_j h[n,j] * Weff[j,k] + cst[k]
// One wave (64 lanes) per batch row; Weff staged in LDS; shuffle reduce.
// ---------------------------------------------------------------------------
__global__ __launch_bounds__(256) void out_kernel(
    const float* __restrict__ h, const float* __restrict__ Weff,
    const float* __restrict__ cst, float* __restrict__ out)
{
    __shared__ float wl[NOUT * NCLS];   // 20 KiB
    __shared__ float cs[NCLS];

    const int t = threadIdx.x;
    for (int i = t; i < NOUT * NCLS; i += 256) wl[i] = Weff[i];
    if (t < NCLS) cs[t] = cst[t];
    __syncthreads();

    const int wave = t >> 6;
    const int lane = t & 63;
    const int n    = blockIdx.x * 4 + wave;

    float acc[NCLS];
#pragma unroll
    for (int k = 0; k < NCLS; ++k) acc[k] = 0.f;

#pragma unroll
    for (int i = 0; i < NOUT / 64; ++i) {
        int   j  = i * 64 + lane;
        float hv = h[n * NOUT + j];
#pragma unroll
        for (int k = 0; k < NCLS; ++k) acc[k] += hv * wl[j * NCLS + k];
    }

#pragma unroll
    for (int k = 0; k < NCLS; ++k) {
#pragma unroll
        for (int off = 32; off; off >>= 1)
            acc[k] += __shfl_down(acc[k], off);
    }

    if (lane == 0) {
#pragma unroll
        for (int k = 0; k < NCLS; ++k)
            out[n * NCLS + k] = acc[k] + cs[k];
    }
}

// ---------------------------------------------------------------------------
extern "C" void kernel_launch(void* const* d_in, const int* in_sizes, int n_in,
                              void* d_out, int out_size, void* d_ws, size_t ws_size,
                              hipStream_t stream)
{
    const float* x     = (const float*)d_in[0];   // [B, P]
    const float* W_fgl = (const float*)d_in[1];   // [COUT, NOUT]
    const float* b_fgl = (const float*)d_in[2];   // [COUT, NOUT]
    const float* W_fc  = (const float*)d_in[3];   // [NOUT*COUT, NCLS]
    const float* b_fc  = (const float*)d_in[4];   // [NCLS]
    const int*   seg   = (const int*)d_in[5];     // [P]
    float*       out   = (float*)d_out;           // [B, NCLS]

    const size_t h_bytes    = (size_t)BATCH * NOUT * sizeof(float);   // 1 MiB
    const size_t weff_bytes = (size_t)NOUT * NCLS * sizeof(float);    // 20 KiB
    const size_t cst_bytes  = (size_t)NCLS * sizeof(float);

    float* h    = (float*)d_ws;
    float* Weff = (float*)((char*)d_ws + h_bytes);
    float* cst  = (float*)((char*)d_ws + h_bytes + weff_bytes);

    // zero h and cst (Weff is fully overwritten, cheap to include)
    hipMemsetAsync(d_ws, 0, h_bytes + weff_bytes + cst_bytes, stream);

    weff_kernel<<<dim3((NOUT + 255) / 256), 256, 0, stream>>>(
        W_fgl, b_fgl, W_fc, b_fc, Weff, cst);

    segsum_kernel<<<dim3(BATCH, CHUNKS), 256, 0, stream>>>(x, seg, h);

    out_kernel<<<dim3(BATCH / 4), 256, 0, stream>>>(h, Weff, cst, out);
}

// Round 2
// 183.729 us; speedup vs baseline: 1.1263x; 1.1263x over previous
//
#include <hip/hip_runtime.h>

#define BATCH 512
#define PIX   65536
#define NOUT  512
#define COUT  4
#define NCLS  10

#define NCOPY 32                  // replicated LDS histogram copies
#define GRP   8                   // float4 loads batched per group
#define F4PT  (PIX / 4 / 256)     // 64 float4 per thread (one row per block)
#define NGRP  (F4PT / GRP)        // 8 groups

// ---------------------------------------------------------------------------
// Kernel 1: Weff[j,k] = sum_c W_fgl[c,j] * W_fc[(c*NOUT+j)*NCLS + k]
//           cst[k]    = sum_{c,j} b_fgl[c,j] * W_fc[(c*NOUT+j)*NCLS + k] + b_fc[k]
// Single block of 512 threads; cst via shuffle + LDS reduce (no atomics).
// ---------------------------------------------------------------------------
__global__ __launch_bounds__(512) void weff_kernel(
    const float* __restrict__ W_fgl, const float* __restrict__ b_fgl,
    const float* __restrict__ W_fc,  const float* __restrict__ b_fc,
    float* __restrict__ Weff, float* __restrict__ cst)
{
    const int j = threadIdx.x;          // 0..511

    float wf[COUT], bf[COUT];
#pragma unroll
    for (int c = 0; c < COUT; ++c) {
        wf[c] = W_fgl[c * NOUT + j];
        bf[c] = b_fgl[c * NOUT + j];
    }

    float cpart[NCLS];
#pragma unroll
    for (int k = 0; k < NCLS; ++k) {
        float w = 0.f, cb = 0.f;
#pragma unroll
        for (int c = 0; c < COUT; ++c) {
            float wfc = W_fc[(c * NOUT + j) * NCLS + k];
            w  += wf[c] * wfc;
            cb += bf[c] * wfc;
        }
        Weff[j * NCLS + k] = w;
        cpart[k] = cb;
    }

    // reduce cpart over all 512 threads: shuffle within wave, LDS across waves
#pragma unroll
    for (int k = 0; k < NCLS; ++k)
#pragma unroll
        for (int off = 32; off; off >>= 1)
            cpart[k] += __shfl_down(cpart[k], off);

    __shared__ float red[8 * NCLS];     // 8 waves
    if ((j & 63) == 0) {
#pragma unroll
        for (int k = 0; k < NCLS; ++k) red[(j >> 6) * NCLS + k] = cpart[k];
    }
    __syncthreads();
    if (j < NCLS) {
        float s = b_fc[j];
#pragma unroll
        for (int w = 0; w < 8; ++w) s += red[w * NCLS + j];
        cst[j] = s;
    }
}

// ---------------------------------------------------------------------------
// Kernel 2: h[n,j] = sum_{p: seg[p]==j} x[n,p]
// One block per batch row. Batched register loads for ILP; 32-copy replicated
// LDS histogram (bank == copy -> always the free 2-way case); no global
// atomics: each block owns its full h row.
// ---------------------------------------------------------------------------
__global__ __launch_bounds__(256) void segsum_kernel(
    const float* __restrict__ x, const int* __restrict__ seg,
    float* __restrict__ h)
{
    const int n  = blockIdx.x;
    const int t  = threadIdx.x;
    const int cp = t & (NCOPY - 1);

    __shared__ float hist[NOUT * NCOPY];   // 64 KiB
    for (int i = t; i < NOUT * NCOPY; i += 256) hist[i] = 0.f;
    __syncthreads();

    const float4* __restrict__ x4 = (const float4*)(x + (size_t)n * PIX);
    const int4*   __restrict__ s4 = (const int4*)seg;

    for (int g = 0; g < NGRP; ++g) {
        float4 xv[GRP];
        int4   sv[GRP];
#pragma unroll
        for (int u = 0; u < GRP; ++u) {
            const int i = (g * GRP + u) * 256 + t;
            xv[u] = x4[i];
            sv[u] = s4[i];
        }
#pragma unroll
        for (int u = 0; u < GRP; ++u) {
            atomicAdd(&hist[sv[u].x * NCOPY + cp], xv[u].x);
            atomicAdd(&hist[sv[u].y * NCOPY + cp], xv[u].y);
            atomicAdd(&hist[sv[u].z * NCOPY + cp], xv[u].z);
            atomicAdd(&hist[sv[u].w * NCOPY + cp], xv[u].w);
        }
    }
    __syncthreads();

    // reduce the 32 copies; rotate start index so lanes hit distinct banks
#pragma unroll
    for (int jj = 0; jj < 2; ++jj) {
        const int j = jj * 256 + t;
        float s = 0.f;
#pragma unroll
        for (int c = 0; c < NCOPY; ++c)
            s += hist[j * NCOPY + ((c + t) & (NCOPY - 1))];
        h[(size_t)n * NOUT + j] = s;
    }
}

// ---------------------------------------------------------------------------
// Kernel 3: out[n,k] = sum_j h[n,j] * Weff[j,k] + cst[k]
// One wave per batch row; Weff staged in LDS; shuffle reduce.
// ---------------------------------------------------------------------------
__global__ __launch_bounds__(256) void out_kernel(
    const float* __restrict__ h, const float* __restrict__ Weff,
    const float* __restrict__ cst, float* __restrict__ out)
{
    __shared__ float wl[NOUT * NCLS];   // 20 KiB
    __shared__ float cs[NCLS];

    const int t = threadIdx.x;
    for (int i = t; i < NOUT * NCLS; i += 256) wl[i] = Weff[i];
    if (t < NCLS) cs[t] = cst[t];
    __syncthreads();

    const int wave = t >> 6;
    const int lane = t & 63;
    const int n    = blockIdx.x * 4 + wave;

    float acc[NCLS];
#pragma unroll
    for (int k = 0; k < NCLS; ++k) acc[k] = 0.f;

#pragma unroll
    for (int i = 0; i < NOUT / 64; ++i) {
        const int   j  = i * 64 + lane;
        const float hv = h[n * NOUT + j];
#pragma unroll
        for (int k = 0; k < NCLS; ++k) acc[k] += hv * wl[j * NCLS + k];
    }

#pragma unroll
    for (int k = 0; k < NCLS; ++k) {
#pragma unroll
        for (int off = 32; off; off >>= 1)
            acc[k] += __shfl_down(acc[k], off);
    }

    if (lane == 0) {
#pragma unroll
        for (int k = 0; k < NCLS; ++k)
            out[n * NCLS + k] = acc[k] + cs[k];
    }
}

// ---------------------------------------------------------------------------
extern "C" void kernel_launch(void* const* d_in, const int* in_sizes, int n_in,
                              void* d_out, int out_size, void* d_ws, size_t ws_size,
                              hipStream_t stream)
{
    const float* x     = (const float*)d_in[0];   // [B, P]
    const float* W_fgl = (const float*)d_in[1];   // [COUT, NOUT]
    const float* b_fgl = (const float*)d_in[2];   // [COUT, NOUT]
    const float* W_fc  = (const float*)d_in[3];   // [NOUT*COUT, NCLS]
    const float* b_fc  = (const float*)d_in[4];   // [NCLS]
    const int*   seg   = (const int*)d_in[5];     // [P]
    float*       out   = (float*)d_out;           // [B, NCLS]

    const size_t h_bytes    = (size_t)BATCH * NOUT * sizeof(float);   // 1 MiB
    const size_t weff_bytes = (size_t)NOUT * NCLS * sizeof(float);    // 20 KiB

    float* h    = (float*)d_ws;
    float* Weff = (float*)((char*)d_ws + h_bytes);
    float* cst  = (float*)((char*)d_ws + h_bytes + weff_bytes);

    // no memsets needed: every ws cell consumed is written by a kernel first
    weff_kernel<<<dim3(1), 512, 0, stream>>>(W_fgl, b_fgl, W_fc, b_fc, Weff, cst);

    segsum_kernel<<<dim3(BATCH), 256, 0, stream>>>(x, seg, h);

    out_kernel<<<dim3(BATCH / 4), 256, 0, stream>>>(h, Weff, cst, out);
}

// Round 3
// 183.650 us; speedup vs baseline: 1.1268x; 1.0004x over previous
//
#include <hip/hip_runtime.h>

#define BATCH 512
#define PIX   65536
#define NOUT  512
#define COUT  4
#define NCLS  10

#define NCOPY 32                  // replicated LDS histogram copies
#define GRP   8                   // float4 loads batched per group
#define F4PT  (PIX / 4 / 256)     // 64 float4 per thread (one row per block)
#define NGRP  (F4PT / GRP)        // 8 groups

// ---------------------------------------------------------------------------
// Kernel 1: Weff[j,k] = sum_c W_fgl[c,j] * W_fc[(c*NOUT+j)*NCLS + k]
//           cst[k]    = sum_{c,j} b_fgl[c,j] * W_fc[(c*NOUT+j)*NCLS + k] + b_fc[k]
// Single block of 512 threads; cst via shuffle + LDS reduce (no atomics).
// ---------------------------------------------------------------------------
__global__ __launch_bounds__(512) void weff_kernel(
    const float* __restrict__ W_fgl, const float* __restrict__ b_fgl,
    const float* __restrict__ W_fc,  const float* __restrict__ b_fc,
    float* __restrict__ Weff, float* __restrict__ cst)
{
    const int j = threadIdx.x;          // 0..511

    float wf[COUT], bf[COUT];
#pragma unroll
    for (int c = 0; c < COUT; ++c) {
        wf[c] = W_fgl[c * NOUT + j];
        bf[c] = b_fgl[c * NOUT + j];
    }

    float cpart[NCLS];
#pragma unroll
    for (int k = 0; k < NCLS; ++k) {
        float w = 0.f, cb = 0.f;
#pragma unroll
        for (int c = 0; c < COUT; ++c) {
            float wfc = W_fc[(c * NOUT + j) * NCLS + k];
            w  += wf[c] * wfc;
            cb += bf[c] * wfc;
        }
        Weff[j * NCLS + k] = w;
        cpart[k] = cb;
    }

    // reduce cpart over all 512 threads: shuffle within wave, LDS across waves
#pragma unroll
    for (int k = 0; k < NCLS; ++k)
#pragma unroll
        for (int off = 32; off; off >>= 1)
            cpart[k] += __shfl_down(cpart[k], off);

    __shared__ float red[8 * NCLS];     // 8 waves
    if ((j & 63) == 0) {
#pragma unroll
        for (int k = 0; k < NCLS; ++k) red[(j >> 6) * NCLS + k] = cpart[k];
    }
    __syncthreads();
    if (j < NCLS) {
        float s = b_fc[j];
#pragma unroll
        for (int w = 0; w < 8; ++w) s += red[w * NCLS + j];
        cst[j] = s;
    }
}

// ---------------------------------------------------------------------------
// Kernel 2: h[n,j] = sum_{p: seg[p]==j} x[n,p]
// One block per batch row. Batched register loads for ILP; 32-copy replicated
// LDS histogram. ONLY change vs round 2: unsafeAtomicAdd -> native ds_add_f32
// instead of the safe-atomics path (suspected CAS loop, ~200cy/wave-instr).
// ---------------------------------------------------------------------------
__global__ __launch_bounds__(256) void segsum_kernel(
    const float* __restrict__ x, const int* __restrict__ seg,
    float* __restrict__ h)
{
    const int n  = blockIdx.x;
    const int t  = threadIdx.x;
    const int cp = t & (NCOPY - 1);

    __shared__ float hist[NOUT * NCOPY];   // 64 KiB
    for (int i = t; i < NOUT * NCOPY; i += 256) hist[i] = 0.f;
    __syncthreads();

    const float4* __restrict__ x4 = (const float4*)(x + (size_t)n * PIX);
    const int4*   __restrict__ s4 = (const int4*)seg;

    for (int g = 0; g < NGRP; ++g) {
        float4 xv[GRP];
        int4   sv[GRP];
#pragma unroll
        for (int u = 0; u < GRP; ++u) {
            const int i = (g * GRP + u) * 256 + t;
            xv[u] = x4[i];
            sv[u] = s4[i];
        }
#pragma unroll
        for (int u = 0; u < GRP; ++u) {
            unsafeAtomicAdd(&hist[sv[u].x * NCOPY + cp], xv[u].x);
            unsafeAtomicAdd(&hist[sv[u].y * NCOPY + cp], xv[u].y);
            unsafeAtomicAdd(&hist[sv[u].z * NCOPY + cp], xv[u].z);
            unsafeAtomicAdd(&hist[sv[u].w * NCOPY + cp], xv[u].w);
        }
    }
    __syncthreads();

    // reduce the 32 copies; rotate start index so lanes hit distinct banks
#pragma unroll
    for (int jj = 0; jj < 2; ++jj) {
        const int j = jj * 256 + t;
        float s = 0.f;
#pragma unroll
        for (int c = 0; c < NCOPY; ++c)
            s += hist[j * NCOPY + ((c + t) & (NCOPY - 1))];
        h[(size_t)n * NOUT + j] = s;
    }
}

// ---------------------------------------------------------------------------
// Kernel 3: out[n,k] = sum_j h[n,j] * Weff[j,k] + cst[k]
// One wave per batch row; Weff staged in LDS; shuffle reduce.
// ---------------------------------------------------------------------------
__global__ __launch_bounds__(256) void out_kernel(
    const float* __restrict__ h, const float* __restrict__ Weff,
    const float* __restrict__ cst, float* __restrict__ out)
{
    __shared__ float wl[NOUT * NCLS];   // 20 KiB
    __shared__ float cs[NCLS];

    const int t = threadIdx.x;
    for (int i = t; i < NOUT * NCLS; i += 256) wl[i] = Weff[i];
    if (t < NCLS) cs[t] = cst[t];
    __syncthreads();

    const int wave = t >> 6;
    const int lane = t & 63;
    const int n    = blockIdx.x * 4 + wave;

    float acc[NCLS];
#pragma unroll
    for (int k = 0; k < NCLS; ++k) acc[k] = 0.f;

#pragma unroll
    for (int i = 0; i < NOUT / 64; ++i) {
        const int   j  = i * 64 + lane;
        const float hv = h[n * NOUT + j];
#pragma unroll
        for (int k = 0; k < NCLS; ++k) acc[k] += hv * wl[j * NCLS + k];
    }

#pragma unroll
    for (int k = 0; k < NCLS; ++k) {
#pragma unroll
        for (int off = 32; off; off >>= 1)
            acc[k] += __shfl_down(acc[k], off);
    }

    if (lane == 0) {
#pragma unroll
        for (int k = 0; k < NCLS; ++k)
            out[n * NCLS + k] = acc[k] + cs[k];
    }
}

// ---------------------------------------------------------------------------
extern "C" void kernel_launch(void* const* d_in, const int* in_sizes, int n_in,
                              void* d_out, int out_size, void* d_ws, size_t ws_size,
                              hipStream_t stream)
{
    const float* x     = (const float*)d_in[0];   // [B, P]
    const float* W_fgl = (const float*)d_in[1];   // [COUT, NOUT]
    const float* b_fgl = (const float*)d_in[2];   // [COUT, NOUT]
    const float* W_fc  = (const float*)d_in[3];   // [NOUT*COUT, NCLS]
    const float* b_fc  = (const float*)d_in[4];   // [NCLS]
    const int*   seg   = (const int*)d_in[5];     // [P]
    float*       out   = (float*)d_out;           // [B, NCLS]

    const size_t h_bytes    = (size_t)BATCH * NOUT * sizeof(float);   // 1 MiB
    const size_t weff_bytes = (size_t)NOUT * NCLS * sizeof(float);    // 20 KiB

    float* h    = (float*)d_ws;
    float* Weff = (float*)((char*)d_ws + h_bytes);
    float* cst  = (float*)((char*)d_ws + h_bytes + weff_bytes);

    // no memsets needed: every ws cell consumed is written by a kernel first
    weff_kernel<<<dim3(1), 512, 0, stream>>>(W_fgl, b_fgl, W_fc, b_fc, Weff, cst);

    segsum_kernel<<<dim3(BATCH), 256, 0, stream>>>(x, seg, h);

    out_kernel<<<dim3(BATCH / 4), 256, 0, stream>>>(h, Weff, cst, out);
}

// Round 4
// 150.025 us; speedup vs baseline: 1.3793x; 1.2241x over previous
//
#include <hip/hip_runtime.h>

#define BATCH 512
#define PIX   65536
#define NOUT  512
#define COUT  4
#define NCLS  10

#define NQ    4
#define QPIX  (PIX / NQ)          // 16384 pixels per quarter
#define QLANE (QPIX / 64)         // 256 sorted ranks per lane per quarter

// ---------------------------------------------------------------------------
// Kernel A: per-quarter bin histogram of seg (global int atomics, ~32/bin).
// counts must be zeroed beforehand.
// ---------------------------------------------------------------------------
__global__ __launch_bounds__(256) void hist_kernel(
    const int* __restrict__ seg, int* __restrict__ counts)
{
    const int p = blockIdx.x * 256 + threadIdx.x;   // 65536 threads
    const int q = p >> 14;
    atomicAdd(&counts[q * NOUT + seg[p]], 1);
}

// ---------------------------------------------------------------------------
// Kernel B: exclusive prefix sum of counts within each quarter -> cursor.
// One block per quarter, Hillis-Steele over 512 elements in LDS.
// ---------------------------------------------------------------------------
__global__ __launch_bounds__(512) void prefix_kernel(
    const int* __restrict__ counts, int* __restrict__ cursor)
{
    __shared__ int sc[NOUT];
    const int q = blockIdx.x, t = threadIdx.x;
    const int v = counts[q * NOUT + t];
    sc[t] = v;
    __syncthreads();
    for (int off = 1; off < NOUT; off <<= 1) {
        const int u = (t >= off) ? sc[t - off] : 0;
        __syncthreads();
        sc[t] += u;
        __syncthreads();
    }
    cursor[q * NOUT + t] = sc[t] - v;   // exclusive
}

// ---------------------------------------------------------------------------
// Kernel C: scatter pixels into bin-sorted order. Rank r within quarter is
// claimed via atomicAdd on cursor. Slot layout is LANE-REMAPPED so that the
// gather kernel reads coalesced (slot s*64+l holds true-rank l*256+s):
// lane l's stride-64 walk visits 256 CONSECUTIVE sorted ranks -> bins
// non-decreasing per lane -> register run accumulation works.
// key packs (bin << 14) | (pixel offset within quarter).
// ---------------------------------------------------------------------------
__global__ __launch_bounds__(256) void scatter_kernel(
    const int* __restrict__ seg, int* __restrict__ cursor,
    unsigned* __restrict__ key)
{
    const int p = blockIdx.x * 256 + threadIdx.x;
    const int q = p >> 14;
    const int b = seg[p];
    const int r = atomicAdd(&cursor[q * NOUT + b], 1);       // 0..16383
    const int slot = ((r & (QLANE - 1)) << 6) + (r >> 8);    // s*64 + l
    key[q * QPIX + slot] = ((unsigned)b << 14) | (unsigned)(p & (QPIX - 1));
}

// ---------------------------------------------------------------------------
// Kernel D: Weff[j,k] = sum_c W_fgl[c,j] * W_fc[(c*NOUT+j)*NCLS + k]
//           cst[k]    = sum_{c,j} b_fgl[c,j] * W_fc[(c*NOUT+j)*NCLS+k] + b_fc[k]
// ---------------------------------------------------------------------------
__global__ __launch_bounds__(512) void weff_kernel(
    const float* __restrict__ W_fgl, const float* __restrict__ b_fgl,
    const float* __restrict__ W_fc,  const float* __restrict__ b_fc,
    float* __restrict__ Weff, float* __restrict__ cst)
{
    const int j = threadIdx.x;          // 0..511

    float wf[COUT], bf[COUT];
#pragma unroll
    for (int c = 0; c < COUT; ++c) {
        wf[c] = W_fgl[c * NOUT + j];
        bf[c] = b_fgl[c * NOUT + j];
    }

    float cpart[NCLS];
#pragma unroll
    for (int k = 0; k < NCLS; ++k) {
        float w = 0.f, cb = 0.f;
#pragma unroll
        for (int c = 0; c < COUT; ++c) {
            const float wfc = W_fc[(c * NOUT + j) * NCLS + k];
            w  += wf[c] * wfc;
            cb += bf[c] * wfc;
        }
        Weff[j * NCLS + k] = w;
        cpart[k] = cb;
    }

#pragma unroll
    for (int k = 0; k < NCLS; ++k)
#pragma unroll
        for (int off = 32; off; off >>= 1)
            cpart[k] += __shfl_down(cpart[k], off);

    __shared__ float red[8 * NCLS];
    if ((j & 63) == 0) {
#pragma unroll
        for (int k = 0; k < NCLS; ++k) red[(j >> 6) * NCLS + k] = cpart[k];
    }
    __syncthreads();
    if (j < NCLS) {
        float s = b_fc[j];
#pragma unroll
        for (int w = 0; w < 8; ++w) s += red[w * NCLS + j];
        cst[j] = s;
    }
}

// ---------------------------------------------------------------------------
// Kernel E: segment sum via sorted gather. Block = one batch row, 4 waves.
// Per quarter: stage 64KB of x into LDS (global_load_lds, coalesced), then
// each lane walks its contiguous sorted run: independent ds_reads (pipelined
// at throughput), register accumulation, rare flush via global f32 atomic.
// h must be zeroed beforehand. 64KB LDS -> 2 blocks/CU (stage/gather overlap).
// ---------------------------------------------------------------------------
__global__ __launch_bounds__(256) void segsum_kernel(
    const float* __restrict__ x, const unsigned* __restrict__ key,
    float* __restrict__ h)
{
    const int n    = blockIdx.x;
    const int t    = threadIdx.x;
    const int w    = t >> 6;
    const int lane = t & 63;

    __shared__ float xq[QPIX];          // 64 KiB
    float4* xq4 = (float4*)xq;
    const float4* src4 = (const float4*)(x + (size_t)n * PIX);
    float* hrow = h + (size_t)n * NOUT;

    for (int q = 0; q < NQ; ++q) {
        // ---- stage quarter q: 16384 floats, 16 x (1KB per wave-instr) ----
#pragma unroll
        for (int i = 0; i < QPIX / 4 / 256; ++i) {   // 16
            __builtin_amdgcn_global_load_lds(
                (const __attribute__((address_space(1))) void*)
                    (src4 + q * (QPIX / 4) + i * 256 + t),
                (__attribute__((address_space(3))) void*)
                    (xq4 + i * 256 + (t & 192)),     // wave-uniform base
                16, 0, 0);
        }
        __syncthreads();                 // drains vmcnt before gather

        // ---- gather: wave w covers sorted slots [w*4096, w*4096+4096) ----
        const unsigned* kq = key + q * QPIX + w * 4096;
        int   cur = -1;
        float acc = 0.f;
#pragma unroll 8
        for (int s = 0; s < 64; ++s) {
            const unsigned k = kq[s * 64 + lane];    // coalesced, L2-hot
            const int   b = (int)(k >> 14);
            const float v = xq[k & (QPIX - 1)];      // independent ds_read
            if (b != cur) {                          // bins non-decreasing
                if (cur >= 0) unsafeAtomicAdd(&hrow[cur], acc);
                cur = b;
                acc = 0.f;
            }
            acc += v;
        }
        if (cur >= 0) unsafeAtomicAdd(&hrow[cur], acc);
        __syncthreads();                 // protect xq before next stage
    }
}

// ---------------------------------------------------------------------------
// Kernel F: out[n,k] = sum_j h[n,j] * Weff[j,k] + cst[k]
// ---------------------------------------------------------------------------
__global__ __launch_bounds__(256) void out_kernel(
    const float* __restrict__ h, const float* __restrict__ Weff,
    const float* __restrict__ cst, float* __restrict__ out)
{
    __shared__ float wl[NOUT * NCLS];   // 20 KiB
    __shared__ float cs[NCLS];

    const int t = threadIdx.x;
    for (int i = t; i < NOUT * NCLS; i += 256) wl[i] = Weff[i];
    if (t < NCLS) cs[t] = cst[t];
    __syncthreads();

    const int wave = t >> 6;
    const int lane = t & 63;
    const int n    = blockIdx.x * 4 + wave;

    float acc[NCLS];
#pragma unroll
    for (int k = 0; k < NCLS; ++k) acc[k] = 0.f;

#pragma unroll
    for (int i = 0; i < NOUT / 64; ++i) {
        const int   j  = i * 64 + lane;
        const float hv = h[n * NOUT + j];
#pragma unroll
        for (int k = 0; k < NCLS; ++k) acc[k] += hv * wl[j * NCLS + k];
    }

#pragma unroll
    for (int k = 0; k < NCLS; ++k) {
#pragma unroll
        for (int off = 32; off; off >>= 1)
            acc[k] += __shfl_down(acc[k], off);
    }

    if (lane == 0) {
#pragma unroll
        for (int k = 0; k < NCLS; ++k)
            out[n * NCLS + k] = acc[k] + cs[k];
    }
}

// ---------------------------------------------------------------------------
extern "C" void kernel_launch(void* const* d_in, const int* in_sizes, int n_in,
                              void* d_out, int out_size, void* d_ws, size_t ws_size,
                              hipStream_t stream)
{
    const float* x     = (const float*)d_in[0];   // [B, P]
    const float* W_fgl = (const float*)d_in[1];   // [COUT, NOUT]
    const float* b_fgl = (const float*)d_in[2];   // [COUT, NOUT]
    const float* W_fc  = (const float*)d_in[3];   // [NOUT*COUT, NCLS]
    const float* b_fc  = (const float*)d_in[4];   // [NCLS]
    const int*   seg   = (const int*)d_in[5];     // [P]
    float*       out   = (float*)d_out;           // [B, NCLS]

    // workspace layout (all offsets 256B-aligned):
    // h[512*512]f32 | counts[4*512]i32 | cursor[4*512]i32 | Weff[512*10]f32
    // | cst[16]f32 | key[65536]u32
    char* ws = (char*)d_ws;
    const size_t h_bytes      = (size_t)BATCH * NOUT * sizeof(float);   // 1 MiB
    const size_t counts_bytes = (size_t)NQ * NOUT * sizeof(int);        // 8 KiB

    float*    h      = (float*)ws;
    int*      counts = (int*)(ws + h_bytes);
    int*      cursor = (int*)(ws + h_bytes + counts_bytes);
    float*    Weff   = (float*)(ws + h_bytes + 2 * counts_bytes);
    float*    cst    = (float*)(ws + h_bytes + 2 * counts_bytes + 20480);
    unsigned* key    = (unsigned*)(ws + h_bytes + 2 * counts_bytes + 20480 + 256);

    // zero h (atomic flush target) and counts (hist target) in one shot
    hipMemsetAsync(d_ws, 0, h_bytes + counts_bytes, stream);

    hist_kernel   <<<dim3(PIX / 256), 256, 0, stream>>>(seg, counts);
    prefix_kernel <<<dim3(NQ),        512, 0, stream>>>(counts, cursor);
    scatter_kernel<<<dim3(PIX / 256), 256, 0, stream>>>(seg, cursor, key);

    weff_kernel   <<<dim3(1),         512, 0, stream>>>(W_fgl, b_fgl, W_fc, b_fc,
                                                        Weff, cst);

    segsum_kernel <<<dim3(BATCH),     256, 0, stream>>>(x, key, h);

    out_kernel    <<<dim3(BATCH / 4), 256, 0, stream>>>(h, Weff, cst, out);
}

// Round 5
// 129.228 us; speedup vs baseline: 1.6013x; 1.1609x over previous
//
#include <hip/hip_runtime.h>

#define BATCH 512
#define PIX   65536
#define NOUT  512
#define COUT  4
#define NCLS  10

#define NSL    8
#define SLPIX  (PIX / NSL)        // 8192 pixels per slice (32 KB)

// ---------------------------------------------------------------------------
// Kernel A: per-slice bin histogram of seg. counts zeroed beforehand.
// ---------------------------------------------------------------------------
__global__ __launch_bounds__(256) void hist_kernel(
    const int* __restrict__ seg, int* __restrict__ counts)
{
    const int p  = blockIdx.x * 256 + threadIdx.x;   // 65536 threads
    const int sl = p >> 13;
    atomicAdd(&counts[sl * NOUT + seg[p]], 1);
}

// ---------------------------------------------------------------------------
// Kernel B: exclusive prefix sum within each slice -> cursor. 8 blocks.
// ---------------------------------------------------------------------------
__global__ __launch_bounds__(512) void prefix_kernel(
    const int* __restrict__ counts, int* __restrict__ cursor)
{
    __shared__ int sc[NOUT];
    const int q = blockIdx.x, t = threadIdx.x;
    const int v = counts[q * NOUT + t];
    sc[t] = v;
    __syncthreads();
    for (int off = 1; off < NOUT; off <<= 1) {
        const int u = (t >= off) ? sc[t - off] : 0;
        __syncthreads();
        sc[t] += u;
        __syncthreads();
    }
    cursor[q * NOUT + t] = sc[t] - v;   // exclusive
}

// ---------------------------------------------------------------------------
// Kernel C: scatter pixels into bin-sorted slots. Within a slice, rank r maps
// to wave w=r>>11, lane=(r&2047)>>5, idx=r&31; slot places lane's 32
// consecutive ranks so a uint4 load per group-of-4 is fully coalesced:
//   slot = w*2048 + (idx>>2)*256 + lane*4 + (idx&3)
// key packs (bin<<13) | (pixel offset within slice).
// ---------------------------------------------------------------------------
__global__ __launch_bounds__(256) void scatter_kernel(
    const int* __restrict__ seg, int* __restrict__ cursor,
    unsigned* __restrict__ key)
{
    const int p  = blockIdx.x * 256 + threadIdx.x;
    const int sl = p >> 13;
    const int b  = seg[p];
    const int r  = atomicAdd(&cursor[sl * NOUT + b], 1);     // 0..8191
    const int w    = r >> 11;
    const int rem  = r & 2047;
    const int lane = rem >> 5;
    const int idx  = rem & 31;
    const int slot = w * 2048 + (idx >> 2) * 256 + lane * 4 + (idx & 3);
    key[sl * SLPIX + slot] = ((unsigned)b << 13) | (unsigned)(p & (SLPIX - 1));
}

// ---------------------------------------------------------------------------
// Kernel D: Weff[j,k] = sum_c W_fgl[c,j] * W_fc[(c*NOUT+j)*NCLS + k]
//           cst[k]    = sum_{c,j} b_fgl[c,j] * W_fc[(c*NOUT+j)*NCLS+k] + b_fc[k]
// ---------------------------------------------------------------------------
__global__ __launch_bounds__(512) void weff_kernel(
    const float* __restrict__ W_fgl, const float* __restrict__ b_fgl,
    const float* __restrict__ W_fc,  const float* __restrict__ b_fc,
    float* __restrict__ Weff, float* __restrict__ cst)
{
    const int j = threadIdx.x;          // 0..511

    float wf[COUT], bf[COUT];
#pragma unroll
    for (int c = 0; c < COUT; ++c) {
        wf[c] = W_fgl[c * NOUT + j];
        bf[c] = b_fgl[c * NOUT + j];
    }

    float cpart[NCLS];
#pragma unroll
    for (int k = 0; k < NCLS; ++k) {
        float w = 0.f, cb = 0.f;
#pragma unroll
        for (int c = 0; c < COUT; ++c) {
            const float wfc = W_fc[(c * NOUT + j) * NCLS + k];
            w  += wf[c] * wfc;
            cb += bf[c] * wfc;
        }
        Weff[j * NCLS + k] = w;
        cpart[k] = cb;
    }

#pragma unroll
    for (int k = 0; k < NCLS; ++k)
#pragma unroll
        for (int off = 32; off; off >>= 1)
            cpart[k] += __shfl_down(cpart[k], off);

    __shared__ float red[8 * NCLS];
    if ((j & 63) == 0) {
#pragma unroll
        for (int k = 0; k < NCLS; ++k) red[(j >> 6) * NCLS + k] = cpart[k];
    }
    __syncthreads();
    if (j < NCLS) {
        float s = b_fc[j];
#pragma unroll
        for (int w = 0; w < 8; ++w) s += red[w * NCLS + j];
        cst[j] = s;
    }
}

// ---------------------------------------------------------------------------
// Kernel E: segment sum, software-pipelined sorted gather.
// Block = one batch row, 4 waves, 2x32KB double-buffered LDS.
// Per slice: (barrier: buf[s] staged) -> issue stage(s+1) -> gather(s) while
// those loads fly. Gather: 32 keys -> regs, 32 ds_reads -> regs (all issued
// before any branch), then branchless-ordered run accumulation with rare
// fire-and-forget global f32 atomic flushes. h zeroed beforehand.
// ---------------------------------------------------------------------------
__device__ __forceinline__ void stage_slice(
    const float4* __restrict__ src4, int sl, float* dst, int w, int lane)
{
    float4* d4 = (float4*)dst;
#pragma unroll
    for (int i = 0; i < 8; ++i)
        __builtin_amdgcn_global_load_lds(
            (const __attribute__((address_space(1))) void*)
                (src4 + sl * (SLPIX / 4) + w * 512 + i * 64 + lane),
            (__attribute__((address_space(3))) void*)
                (d4 + w * 512 + i * 64),          // wave-uniform base
            16, 0, 0);
}

__global__ __launch_bounds__(256) void segsum_kernel(
    const float* __restrict__ x, const unsigned* __restrict__ key,
    float* __restrict__ h)
{
    const int n    = blockIdx.x;
    const int t    = threadIdx.x;
    const int w    = t >> 6;
    const int lane = t & 63;

    __shared__ float xs[2][SLPIX];      // 64 KiB
    const float4* src4 = (const float4*)(x + (size_t)n * PIX);
    float* hrow = h + (size_t)n * NOUT;

    stage_slice(src4, 0, &xs[0][0], w, lane);

    int   cur = -1;
    float acc = 0.f;

    for (int sl = 0; sl < NSL; ++sl) {
        __syncthreads();   // compiler drains vmcnt -> buf[sl&1] fully staged

        if (sl + 1 < NSL)
            stage_slice(src4, sl + 1, &xs[(sl + 1) & 1][0], w, lane);

        // ---- keys for this wave's 2048 sorted ranks: 8 coalesced uint4 ----
        unsigned kk[32];
        {
            const uint4* kq = (const uint4*)key + (size_t)sl * (SLPIX / 4) + w * 512;
#pragma unroll
            for (int g = 0; g < 8; ++g) {
                const uint4 kv = kq[g * 64 + lane];
                kk[g * 4 + 0] = kv.x; kk[g * 4 + 1] = kv.y;
                kk[g * 4 + 2] = kv.z; kk[g * 4 + 3] = kv.w;
            }
        }

        // ---- all 32 LDS gathers issued before any accumulation ----
        const float* bufp = &xs[sl & 1][0];
        float v[32];
#pragma unroll
        for (int j = 0; j < 32; ++j) v[j] = bufp[kk[j] & (SLPIX - 1)];

        // ---- run accumulation over non-decreasing bins ----
#pragma unroll
        for (int j = 0; j < 32; ++j) {
            const int b = (int)(kk[j] >> 13);
            if (b != cur) {
                if (cur >= 0) unsafeAtomicAdd(&hrow[cur], acc);
                cur = b;
                acc = v[j];
            } else {
                acc += v[j];
            }
        }
    }
    if (cur >= 0) unsafeAtomicAdd(&hrow[cur], acc);
}

// ---------------------------------------------------------------------------
// Kernel F: out[n,k] = sum_j h[n,j] * Weff[j,k] + cst[k]
// ---------------------------------------------------------------------------
__global__ __launch_bounds__(256) void out_kernel(
    const float* __restrict__ h, const float* __restrict__ Weff,
    const float* __restrict__ cst, float* __restrict__ out)
{
    __shared__ float wl[NOUT * NCLS];   // 20 KiB
    __shared__ float cs[NCLS];

    const int t = threadIdx.x;
    for (int i = t; i < NOUT * NCLS; i += 256) wl[i] = Weff[i];
    if (t < NCLS) cs[t] = cst[t];
    __syncthreads();

    const int wave = t >> 6;
    const int lane = t & 63;
    const int n    = blockIdx.x * 4 + wave;

    float acc[NCLS];
#pragma unroll
    for (int k = 0; k < NCLS; ++k) acc[k] = 0.f;

#pragma unroll
    for (int i = 0; i < NOUT / 64; ++i) {
        const int   j  = i * 64 + lane;
        const float hv = h[n * NOUT + j];
#pragma unroll
        for (int k = 0; k < NCLS; ++k) acc[k] += hv * wl[j * NCLS + k];
    }

#pragma unroll
    for (int k = 0; k < NCLS; ++k) {
#pragma unroll
        for (int off = 32; off; off >>= 1)
            acc[k] += __shfl_down(acc[k], off);
    }

    if (lane == 0) {
#pragma unroll
        for (int k = 0; k < NCLS; ++k)
            out[n * NCLS + k] = acc[k] + cs[k];
    }
}

// ---------------------------------------------------------------------------
extern "C" void kernel_launch(void* const* d_in, const int* in_sizes, int n_in,
                              void* d_out, int out_size, void* d_ws, size_t ws_size,
                              hipStream_t stream)
{
    const float* x     = (const float*)d_in[0];   // [B, P]
    const float* W_fgl = (const float*)d_in[1];   // [COUT, NOUT]
    const float* b_fgl = (const float*)d_in[2];   // [COUT, NOUT]
    const float* W_fc  = (const float*)d_in[3];   // [NOUT*COUT, NCLS]
    const float* b_fc  = (const float*)d_in[4];   // [NCLS]
    const int*   seg   = (const int*)d_in[5];     // [P]
    float*       out   = (float*)d_out;           // [B, NCLS]

    // ws layout: h[512*512]f32 | counts[8*512]i32 | cursor[8*512]i32
    //            | Weff[512*10]f32 | cst[64]f32 | key[65536]u32
    char* ws = (char*)d_ws;
    const size_t h_bytes      = (size_t)BATCH * NOUT * sizeof(float);   // 1 MiB
    const size_t counts_bytes = (size_t)NSL * NOUT * sizeof(int);       // 16 KiB

    float*    h      = (float*)ws;
    int*      counts = (int*)(ws + h_bytes);
    int*      cursor = (int*)(ws + h_bytes + counts_bytes);
    float*    Weff   = (float*)(ws + h_bytes + 2 * counts_bytes);
    float*    cst    = (float*)(ws + h_bytes + 2 * counts_bytes + 20480);
    unsigned* key    = (unsigned*)(ws + h_bytes + 2 * counts_bytes + 20480 + 256);

    // zero h (atomic flush target) and counts (hist target)
    hipMemsetAsync(d_ws, 0, h_bytes + counts_bytes, stream);

    hist_kernel   <<<dim3(PIX / 256), 256, 0, stream>>>(seg, counts);
    prefix_kernel <<<dim3(NSL),       512, 0, stream>>>(counts, cursor);
    scatter_kernel<<<dim3(PIX / 256), 256, 0, stream>>>(seg, cursor, key);

    weff_kernel   <<<dim3(1),         512, 0, stream>>>(W_fgl, b_fgl, W_fc, b_fc,
                                                        Weff, cst);

    segsum_kernel <<<dim3(BATCH),     256, 0, stream>>>(x, key, h);

    out_kernel    <<<dim3(BATCH / 4), 256, 0, stream>>>(h, Weff, cst, out);
}